// Round 15
// baseline (226.367 us; speedup 1.0000x reference)
//
#include <hip/hip_runtime.h>
#include <math.h>

#define N_NODES 50000
#define N_EDGES 800000
#define DIN 64
#define HC 256      // H*C
#define NH 4        // heads
#define CPH 64      // channels per head
#define ED 11
#define NPAD 50176  // 196*256
#define NB_SCAN 196
#define NTILE 3125       // N_NODES/16
#define SCAT_BLKS 3125   // N_EDGES/256
#define PROJ_BLKS 782    // ceil(NTILE/4)
#define FOLD_THREADS 45056

typedef unsigned int uint;
typedef unsigned short ushort_t;
using short8 = __attribute__((ext_vector_type(8))) short;
using f32x4  = __attribute__((ext_vector_type(4))) float;

__device__ __forceinline__ ushort_t f2bf(float f) {
    uint u = __float_as_uint(f);
    u = (u + 0x7FFFu + ((u >> 16) & 1u)) >> 16;   // RTNE
    return (ushort_t)u;
}
__device__ __forceinline__ float bf2f(ushort_t h) {
    return __uint_as_float(((uint)h) << 16);
}

// ---------------------------------------------------------------------------
// prep_hist: weight folds (first 45056 threads) FUSED with the dst-degree
// histogram (remaining blocks). deg/cursor pre-zeroed by hipMemsetAsync.
// Frag layout (16x16x32): element (k,n) -> lane = (n&15)|(((k>>3)&3)<<4),
// j=k&7, kstep=k>>5; arrays base[f*512+lane*8+j].
__global__ void prep_hist(const float* __restrict__ Wq, const float* __restrict__ Wk,
                          const float* __restrict__ Wv, const float* __restrict__ We,
                          const float* __restrict__ Wskip, const float* __restrict__ Wlin,
                          ushort_t* __restrict__ GTB, ushort_t* __restrict__ M2B,
                          ushort_t* __restrict__ WFB,
                          const int* __restrict__ dst, int* __restrict__ deg) {
    const int g = blockIdx.x * 256 + threadIdx.x;
    if (g < 16384) {                       // GTB: (d, hc)
        const int d = g >> 8, hc = g & 255;
        const int hb = hc & 192, dp = hc & 63;
        const float* bq = Wq + d * HC + hb;
        const float* bk = Wk + dp * HC + hb;
        float v = 0.f;
        #pragma unroll 8
        for (int c = 0; c < 64; ++c) v = fmaf(bq[c], bk[c], v);
        const int l = (hc & 15) | (((d >> 3) & 3) << 4);
        GTB[(((hc >> 4) * 2 + (d >> 5)) * 64 + l) * 8 + (d & 7)] = f2bf(v);
    } else if (g < 20480) {                // M2B: (d, col<64), active col<48
        const int gm = g - 16384;
        const int d = gm >> 6, col = gm & 63;
        if (col < 48) {
            float v = 0.f;
            if (col < 44) {
                const int h = col / 11, j = col - h * 11;
                const float* wq = Wq + d * HC + h * 64;
                const float* we = We + j * HC + h * 64;
                #pragma unroll 8
                for (int c = 0; c < 64; ++c) v = fmaf(wq[c], we[c], v);
            }
            const int l = (col & 15) | (((d >> 3) & 3) << 4);
            M2B[(((col >> 4) * 2 + (d >> 5)) * 64 + l) * 8 + (d & 7)] = f2bf(v);
        }
    } else if (g < 20480 + 24576) {        // WFB: (k<384, o<64)
        const int gm = g - 20480;
        const int k = gm >> 6, o = gm & 63;
        float v = 0.f;
        if (k < 256) {
            const int h = k >> 6, d = k & 63;
            const float* wv = Wv + d * HC + h * 64;
            const float* wl = Wlin + (h * 64) * CPH + o;
            #pragma unroll 8
            for (int c = 0; c < 64; ++c) v = fmaf(wv[c], wl[(size_t)c * CPH], v);
        } else if (k < 320) {
            const int d = k - 256;
            const float* wsk = Wskip + d * HC;
            const float* wl = Wlin + o;
            #pragma unroll 8
            for (int k2 = 0; k2 < 256; ++k2) v = fmaf(wsk[k2], wl[(size_t)k2 * CPH], v);
        } else if (k < 364) {
            const int r = k - 320;
            const int h = r / 11, j = r - h * 11;
            const float* we = We + j * HC + h * 64;
            const float* wl = Wlin + (h * 64) * CPH + o;
            #pragma unroll 8
            for (int c = 0; c < 64; ++c) v = fmaf(we[c], wl[(size_t)c * CPH], v);
        }
        const int l = (o & 15) | (((k >> 3) & 3) << 4);
        WFB[(((k >> 5) * 4 + (o >> 4)) * 64 + l) * 8 + (k & 7)] = f2bf(v);
    } else {                               // histogram
        const int e = g - FOLD_THREADS;
        if (e < N_EDGES) atomicAdd(&deg[dst[e]], 1);
    }
}

// ---------------------------------------------------------------------------
// CSR scans.
__global__ void scan_local(const int* __restrict__ deg, int* __restrict__ rowstart,
                           int* __restrict__ psum) {
    __shared__ int s[256];
    const int b = blockIdx.x, t = threadIdx.x, i = b * 256 + t;
    const int v = (i < N_NODES) ? deg[i] : 0;
    s[t] = v;
    __syncthreads();
    for (int off = 1; off < 256; off <<= 1) {
        const int xr = (t >= off) ? s[t - off] : 0;
        __syncthreads();
        s[t] += xr;
        __syncthreads();
    }
    if (i < N_NODES) rowstart[i] = s[t] - v;  // exclusive within block
    if (t == 255) psum[b] = s[255];
}

__global__ void scan_add(int* __restrict__ rowstart, const int* __restrict__ psum) {
    __shared__ int s[256];
    __shared__ int ex[256];
    const int b = blockIdx.x, t = threadIdx.x;
    const int v = (t < NB_SCAN) ? psum[t] : 0;
    s[t] = v;
    __syncthreads();
    for (int off = 1; off < 256; off <<= 1) {
        const int xr = (t >= off) ? s[t - off] : 0;
        __syncthreads();
        s[t] += xr;
        __syncthreads();
    }
    ex[t] = s[t] - v;   // exclusive
    __syncthreads();
    const int i = b * 256 + t;
    if (i < N_NODES) rowstart[i] += ex[b];
}

// ---------------------------------------------------------------------------
// scatter_proj: FUSED edge scatter (blocks < SCAT_BLKS) + MFMA node
// projection (remaining blocks, 4 wave-tiles of 16 nodes each).
__global__ void __launch_bounds__(256) scatter_proj(
        const int* __restrict__ src, const int* __restrict__ dst,
        const float* __restrict__ ea,
        const int* __restrict__ rowstart, int* __restrict__ cursor,
        uint* __restrict__ EREC,
        const float* __restrict__ x,
        const ushort_t* __restrict__ GTB, const ushort_t* __restrict__ M2B,
        float* __restrict__ P, float* __restrict__ QWE,
        ushort_t* __restrict__ xb) {
    const int bid = blockIdx.x;
    const int t = threadIdx.x;
    if (bid < SCAT_BLKS) {
        // ---- scatter: 32B records [bf16 ea[11], pad, int src, pad] ----
        const int e = bid * 256 + t;
        const int d = dst[e];
        const int pos = atomicAdd(&cursor[d], 1);
        const size_t idx = (size_t)rowstart[d] + pos;
        const float* in = ea + (size_t)e * ED;
        uint w[8];
        #pragma unroll
        for (int jj = 0; jj < 5; ++jj)
            w[jj] = (uint)f2bf(in[2 * jj]) | ((uint)f2bf(in[2 * jj + 1]) << 16);
        w[5] = (uint)f2bf(in[10]);
        w[6] = (uint)src[e];
        w[7] = 0u;
        uint4* o = (uint4*)(EREC + idx * 8);
        o[0] = make_uint4(w[0], w[1], w[2], w[3]);
        o[1] = make_uint4(w[4], w[5], w[6], w[7]);
        return;
    }
    // ---- node projection: P = x@G, QWE = x@M2, xb = bf16(x) ----
    const int lane = t & 63;
    const int tile = (bid - SCAT_BLKS) * 4 + (t >> 6);
    if (tile >= NTILE) return;
    const int n0 = tile * 16;
    const int m = lane & 15, kb = (lane >> 4) * 8;

    short8 a[2];
    #pragma unroll
    for (int ks = 0; ks < 2; ++ks) {
        const float* px = x + (size_t)(n0 + m) * DIN + ks * 32 + kb;
        const float4 u = *(const float4*)px;
        const float4 w4 = *(const float4*)(px + 4);
        short8 av;
        av[0] = (short)f2bf(u.x); av[1] = (short)f2bf(u.y);
        av[2] = (short)f2bf(u.z); av[3] = (short)f2bf(u.w);
        av[4] = (short)f2bf(w4.x); av[5] = (short)f2bf(w4.y);
        av[6] = (short)f2bf(w4.z); av[7] = (short)f2bf(w4.w);
        a[ks] = av;
        *(short8*)(xb + (size_t)(n0 + m) * DIN + ks * 32 + kb) = av;
    }

    const short8* GB = (const short8*)GTB;
    const short8* MB = (const short8*)M2B;
    const int rw = (lane >> 4) * 4, cc = lane & 15;

    #pragma unroll
    for (int nt = 0; nt < 16; ++nt) {
        f32x4 c = {0.f, 0.f, 0.f, 0.f};
        c = __builtin_amdgcn_mfma_f32_16x16x32_bf16(a[0], GB[(nt * 2 + 0) * 64 + lane], c, 0, 0, 0);
        c = __builtin_amdgcn_mfma_f32_16x16x32_bf16(a[1], GB[(nt * 2 + 1) * 64 + lane], c, 0, 0, 0);
        #pragma unroll
        for (int r = 0; r < 4; ++r)
            P[(size_t)(n0 + rw + r) * HC + nt * 16 + cc] = c[r];
    }
    #pragma unroll
    for (int q = 0; q < 3; ++q) {
        f32x4 c = {0.f, 0.f, 0.f, 0.f};
        c = __builtin_amdgcn_mfma_f32_16x16x32_bf16(a[0], MB[(q * 2 + 0) * 64 + lane], c, 0, 0, 0);
        c = __builtin_amdgcn_mfma_f32_16x16x32_bf16(a[1], MB[(q * 2 + 1) * 64 + lane], c, 0, 0, 0);
        const int col = q * 16 + cc;
        if (col < 44) {
            #pragma unroll
            for (int r = 0; r < 4; ++r)
                QWE[(size_t)(n0 + rw + r) * 44 + col] = c[r];
        }
    }
}

// ---------------------------------------------------------------------------
// K2 (FUSED): attention (attn8's proven 4-edge-batch direct-softmax loop)
// + in-block finalize. 4 waves = 4 nodes; each wave stages its 384-value
// bf16 row [xagg|x|TO|0] into LDS, then computes one 16-col quadrant of
// y[4x64] = row[4x384] @ WFT via 12 MFMAs (A rows 4..15 zero; D rows >=4
// discarded -- MFMA has no cross-row mixing).
__global__ void __launch_bounds__(256) attnF(const uint* __restrict__ EREC,
                      const float* __restrict__ P,
                      const float* __restrict__ QWE,
                      const ushort_t* __restrict__ xb,
                      const int* __restrict__ rowstart,
                      const int* __restrict__ deg,
                      const ushort_t* __restrict__ WFB,
                      float* __restrict__ y) {
    __shared__ ushort_t rowbuf[4][384];   // 3 KB
    const int t = threadIdx.x;
    const int lane = t & 63;
    const int wid = t >> 6;
    const int n = blockIdx.x * 4 + wid;   // N_NODES % 4 == 0
    const int h = lane >> 4;              // head
    const int j = lane & 15;              // slot: channels 4j..4j+3 of this head

    const float4 p4 = ((const float4*)P)[(size_t)n * 64 + lane];
    const float qwe = (j < ED) ? QWE[(size_t)n * 44 + h * 11 + j] : 0.f;

    const int beg = __builtin_amdgcn_readfirstlane(rowstart[n]);
    const int dc  = __builtin_amdgcn_readfirstlane(deg[n]);

    float den = 0.f, Tacc = 0.f;
    float4 acc = {0.f, 0.f, 0.f, 0.f};

    const int dc4 = dc & ~3;
    int i = 0;
    for (; i < dc4; i += 4) {
        const ushort_t* rr = (const ushort_t*)(EREC + (size_t)(beg + i) * 8);
        const int s0 = __builtin_amdgcn_readfirstlane(((const int*)rr)[6]);
        const int s1 = __builtin_amdgcn_readfirstlane(((const int*)rr)[14]);
        const int s2 = __builtin_amdgcn_readfirstlane(((const int*)rr)[22]);
        const int s3 = __builtin_amdgcn_readfirstlane(((const int*)rr)[30]);
        const float ea0 = (j < ED) ? bf2f(rr[j]) : 0.f;
        const float ea1 = (j < ED) ? bf2f(rr[16 + j]) : 0.f;
        const float ea2 = (j < ED) ? bf2f(rr[32 + j]) : 0.f;
        const float ea3 = (j < ED) ? bf2f(rr[48 + j]) : 0.f;
        const ushort4 x0 = ((const ushort4*)(xb + (size_t)s0 * DIN))[j];
        const ushort4 x1 = ((const ushort4*)(xb + (size_t)s1 * DIN))[j];
        const ushort4 x2 = ((const ushort4*)(xb + (size_t)s2 * DIN))[j];
        const ushort4 x3 = ((const ushort4*)(xb + (size_t)s3 * DIN))[j];

        float p0 = p4.x * bf2f(x0.x) + p4.y * bf2f(x0.y)
                 + p4.z * bf2f(x0.z) + p4.w * bf2f(x0.w) + ea0 * qwe;
        float p1 = p4.x * bf2f(x1.x) + p4.y * bf2f(x1.y)
                 + p4.z * bf2f(x1.z) + p4.w * bf2f(x1.w) + ea1 * qwe;
        float p2 = p4.x * bf2f(x2.x) + p4.y * bf2f(x2.y)
                 + p4.z * bf2f(x2.z) + p4.w * bf2f(x2.w) + ea2 * qwe;
        float p3 = p4.x * bf2f(x3.x) + p4.y * bf2f(x3.y)
                 + p4.z * bf2f(x3.z) + p4.w * bf2f(x3.w) + ea3 * qwe;

        p0 += __shfl_xor(p0, 1, 64);  p1 += __shfl_xor(p1, 1, 64);
        p2 += __shfl_xor(p2, 1, 64);  p3 += __shfl_xor(p3, 1, 64);
        p0 += __shfl_xor(p0, 2, 64);  p1 += __shfl_xor(p1, 2, 64);
        p2 += __shfl_xor(p2, 2, 64);  p3 += __shfl_xor(p3, 2, 64);
        p0 += __shfl_xor(p0, 4, 64);  p1 += __shfl_xor(p1, 4, 64);
        p2 += __shfl_xor(p2, 4, 64);  p3 += __shfl_xor(p3, 4, 64);
        p0 += __shfl_xor(p0, 8, 64);  p1 += __shfl_xor(p1, 8, 64);
        p2 += __shfl_xor(p2, 8, 64);  p3 += __shfl_xor(p3, 8, 64);

        const float e0 = __expf(p0 * 0.125f);
        const float e1 = __expf(p1 * 0.125f);
        const float e2 = __expf(p2 * 0.125f);
        const float e3 = __expf(p3 * 0.125f);

        acc.x = fmaf(e0, bf2f(x0.x), fmaf(e1, bf2f(x1.x),
                fmaf(e2, bf2f(x2.x), fmaf(e3, bf2f(x3.x), acc.x))));
        acc.y = fmaf(e0, bf2f(x0.y), fmaf(e1, bf2f(x1.y),
                fmaf(e2, bf2f(x2.y), fmaf(e3, bf2f(x3.y), acc.y))));
        acc.z = fmaf(e0, bf2f(x0.z), fmaf(e1, bf2f(x1.z),
                fmaf(e2, bf2f(x2.z), fmaf(e3, bf2f(x3.z), acc.z))));
        acc.w = fmaf(e0, bf2f(x0.w), fmaf(e1, bf2f(x1.w),
                fmaf(e2, bf2f(x2.w), fmaf(e3, bf2f(x3.w), acc.w))));
        den += (e0 + e1) + (e2 + e3);
        Tacc = fmaf(e0, ea0, fmaf(e1, ea1, fmaf(e2, ea2, fmaf(e3, ea3, Tacc))));
    }
    for (; i < dc; ++i) {                       // tail
        const ushort_t* r0 = (const ushort_t*)(EREC + (size_t)(beg + i) * 8);
        const int s0 = __builtin_amdgcn_readfirstlane(((const int*)r0)[6]);
        const float ea0 = (j < ED) ? bf2f(r0[j]) : 0.f;
        const ushort4 x0 = ((const ushort4*)(xb + (size_t)s0 * DIN))[j];
        float p0 = p4.x * bf2f(x0.x) + p4.y * bf2f(x0.y)
                 + p4.z * bf2f(x0.z) + p4.w * bf2f(x0.w) + ea0 * qwe;
        p0 += __shfl_xor(p0, 1, 64);
        p0 += __shfl_xor(p0, 2, 64);
        p0 += __shfl_xor(p0, 4, 64);
        p0 += __shfl_xor(p0, 8, 64);
        const float e0 = __expf(p0 * 0.125f);
        acc.x = fmaf(e0, bf2f(x0.x), acc.x);
        acc.y = fmaf(e0, bf2f(x0.y), acc.y);
        acc.z = fmaf(e0, bf2f(x0.z), acc.z);
        acc.w = fmaf(e0, bf2f(x0.w), acc.w);
        den += e0;
        Tacc = fmaf(e0, ea0, Tacc);
    }

    // ---- stage row into LDS: [xagg(256) | x(64) | TO(44) | 0(20)] ----
    const float inv = (den > 0.f) ? 1.f / den : 0.f;
    ushort4 ob;
    ob.x = f2bf(acc.x * inv); ob.y = f2bf(acc.y * inv);
    ob.z = f2bf(acc.z * inv); ob.w = f2bf(acc.w * inv);
    *(ushort4*)(&rowbuf[wid][lane * 4]) = ob;              // xagg
    if (lane < 8) {                                        // x copy (bf16)
        const uint4 v = *(const uint4*)(xb + (size_t)n * DIN + lane * 8);
        *(uint4*)(&rowbuf[wid][256 + lane * 8]) = v;
    }
    if (j < ED) rowbuf[wid][320 + h * 11 + j] = f2bf(Tacc * inv);  // TO
    if (lane >= 44) rowbuf[wid][320 + lane] = 0;           // pad 364..383
    __syncthreads();

    // ---- finalize: wave wid computes col quadrant wid of y[4x64] ----
    const int m = lane & 15, kb = (lane >> 4) * 8;
    const short8* WB = (const short8*)WFB;
    f32x4 c = {0.f, 0.f, 0.f, 0.f};
    #pragma unroll
    for (int ks = 0; ks < 12; ++ks) {
        short8 av = {0, 0, 0, 0, 0, 0, 0, 0};
        if (m < 4) av = *(const short8*)(&rowbuf[m][ks * 32 + kb]);
        c = __builtin_amdgcn_mfma_f32_16x16x32_bf16(av, WB[(ks * 4 + wid) * 64 + lane], c, 0, 0, 0);
    }
    if (lane < 16) {                       // D rows 0..3 live in lanes 0..15
        const int n0 = blockIdx.x * 4;
        #pragma unroll
        for (int r = 0; r < 4; ++r)
            y[(size_t)(n0 + r) * CPH + wid * 16 + lane] = c[r];
    }
}

// ---------------------------------------------------------------------------
extern "C" void kernel_launch(void* const* d_in, const int* in_sizes, int n_in,
                              void* d_out, int out_size, void* d_ws, size_t ws_size,
                              hipStream_t stream) {
    const float* x     = (const float*)d_in[0];
    const float* ea    = (const float*)d_in[1];
    const int*   eidx  = (const int*)  d_in[2];
    const float* Wq    = (const float*)d_in[3];
    const float* Wk    = (const float*)d_in[4];
    const float* Wv    = (const float*)d_in[5];
    const float* We    = (const float*)d_in[6];
    const float* Wskip = (const float*)d_in[7];
    const float* Wlin  = (const float*)d_in[8];
    float* out = (float*)d_out;

    float* ws   = (float*)d_ws;
    float* P    = ws;                            // N*256 f32
    float* QWE  = P + (size_t)N_NODES * HC;      // N*44 f32
    ushort_t* GTB  = (ushort_t*)(QWE + (size_t)N_NODES * 44);  // 16384 sh
    ushort_t* M2B  = GTB + 16384;                // 3072 sh
    ushort_t* WFB  = M2B + 3072;                 // 24576 sh
    ushort_t* xb   = WFB + 24576;                // N*64 sh
    int* deg     = (int*)(xb + (size_t)N_NODES * DIN);  // NPAD
    int* cursor  = deg + NPAD;                   // NPAD (zeroed with deg)
    int* rowstart= cursor + NPAD;                // NPAD
    int* psum    = rowstart + NPAD;              // 256
    uint* EREC   = (uint*)(psum + 256);          // E*32B

    const int* src = eidx;
    const int* dst = eidx + N_EDGES;

    hipMemsetAsync(deg, 0, (size_t)2 * NPAD * sizeof(int), stream);
    prep_hist<<<(FOLD_THREADS + N_EDGES + 255) / 256, 256, 0, stream>>>(
        Wq, Wk, Wv, We, Wskip, Wlin, GTB, M2B, WFB, dst, deg);
    scan_local<<<NB_SCAN, 256, 0, stream>>>(deg, rowstart, psum);
    scan_add<<<NB_SCAN, 256, 0, stream>>>(rowstart, psum);
    scatter_proj<<<SCAT_BLKS + PROJ_BLKS, 256, 0, stream>>>(
        src, dst, ea, rowstart, cursor, EREC, x, GTB, M2B, P, QWE, xb);
    attnF<<<N_NODES / 4, 256, 0, stream>>>(EREC, P, QWE, xb, rowstart, deg, WFB, out);
}

// Round 17
// 184.419 us; speedup vs baseline: 1.2275x; 1.2275x over previous
//
#include <hip/hip_runtime.h>
#include <math.h>

#define N_NODES 50000
#define N_EDGES 800000
#define DIN 64
#define HC 256      // H*C
#define NH 4        // heads
#define CPH 64      // channels per head
#define ED 11
#define NPAD 50176  // 196*256
#define NB_SCAN 196
#define NTILE 3125       // N_NODES/16
#define SCAT_BLKS 3125   // N_EDGES/256
#define PROJ_BLKS 782    // ceil(NTILE/4)
#define FOLD_THREADS 45056

typedef unsigned int uint;
typedef unsigned short ushort_t;
using short8 = __attribute__((ext_vector_type(8))) short;
using f32x4  = __attribute__((ext_vector_type(4))) float;

__device__ __forceinline__ ushort_t f2bf(float f) {
    uint u = __float_as_uint(f);
    u = (u + 0x7FFFu + ((u >> 16) & 1u)) >> 16;   // RTNE
    return (ushort_t)u;
}
__device__ __forceinline__ float bf2f(ushort_t h) {
    return __uint_as_float(((uint)h) << 16);
}

// ---------------------------------------------------------------------------
// prep_hist: weight folds into bf16 MFMA B-fragments + dst-degree histogram.
// Frag layout (16x16x32): element (k,n) -> lane = (n&15)|(((k>>3)&3)<<4),
// j=k&7, kstep=k>>5; arrays base[f*512+lane*8+j].
//  NPB: 320 cols x K=64: cols 0..255 = G_h = Wq_h·Wk_hT; cols 256..319 =
//       [h=cm>>4, jj=cm&15] = (jj<11 ? Wq_h·We_jj fold : 0). 40 frags.
//  WFB: [Wv·Wlin | Wskip·Wlin | We·Wlin | 0] (K=384, 64 cols), f = kstep*4+(col>>4)
__global__ void prep_hist(const float* __restrict__ Wq, const float* __restrict__ Wk,
                          const float* __restrict__ Wv, const float* __restrict__ We,
                          const float* __restrict__ Wskip, const float* __restrict__ Wlin,
                          ushort_t* __restrict__ NPB, ushort_t* __restrict__ WFB,
                          const int* __restrict__ dst, int* __restrict__ deg) {
    const int g = blockIdx.x * 256 + threadIdx.x;
    if (g < 16384) {                       // NPB cols 0..255 (G)
        const int d = g >> 8, hc = g & 255;
        const int hb = hc & 192, dp = hc & 63;
        const float* bq = Wq + d * HC + hb;
        const float* bk = Wk + dp * HC + hb;
        float v = 0.f;
        #pragma unroll 8
        for (int c = 0; c < 64; ++c) v = fmaf(bq[c], bk[c], v);
        const int l = (hc & 15) | (((d >> 3) & 3) << 4);
        NPB[(((hc >> 4) * 2 + (d >> 5)) * 64 + l) * 8 + (d & 7)] = f2bf(v);
    } else if (g < 20480) {                // NPB cols 256..319 (QWE fold, padded)
        const int gm = g - 16384;
        const int d = gm >> 6, cm = gm & 63;
        const int h = cm >> 4, jj = cm & 15;
        float v = 0.f;
        if (jj < ED) {
            const float* wq = Wq + d * HC + h * 64;
            const float* we = We + jj * HC + h * 64;
            #pragma unroll 8
            for (int c = 0; c < 64; ++c) v = fmaf(wq[c], we[c], v);
        }
        const int col = 256 + cm;
        const int l = (cm & 15) | (((d >> 3) & 3) << 4);
        NPB[(((col >> 4) * 2 + (d >> 5)) * 64 + l) * 8 + (d & 7)] = f2bf(v);
    } else if (g < 20480 + 24576) {        // WFB: (k<384, o<64)
        const int gm = g - 20480;
        const int k = gm >> 6, o = gm & 63;
        float v = 0.f;
        if (k < 256) {
            const int h = k >> 6, d = k & 63;
            const float* wv = Wv + d * HC + h * 64;
            const float* wl = Wlin + (h * 64) * CPH + o;
            #pragma unroll 8
            for (int c = 0; c < 64; ++c) v = fmaf(wv[c], wl[(size_t)c * CPH], v);
        } else if (k < 320) {
            const int d = k - 256;
            const float* wsk = Wskip + d * HC;
            const float* wl = Wlin + o;
            #pragma unroll 8
            for (int k2 = 0; k2 < 256; ++k2) v = fmaf(wsk[k2], wl[(size_t)k2 * CPH], v);
        } else if (k < 364) {
            const int r = k - 320;
            const int h = r / 11, j = r - h * 11;
            const float* we = We + j * HC + h * 64;
            const float* wl = Wlin + (h * 64) * CPH + o;
            #pragma unroll 8
            for (int c = 0; c < 64; ++c) v = fmaf(we[c], wl[(size_t)c * CPH], v);
        }
        const int l = (o & 15) | (((k >> 3) & 3) << 4);
        WFB[(((k >> 5) * 4 + (o >> 4)) * 64 + l) * 8 + (k & 7)] = f2bf(v);
    } else {                               // histogram
        const int e = g - FOLD_THREADS;
        if (e < N_EDGES) atomicAdd(&deg[dst[e]], 1);
    }
}

// ---------------------------------------------------------------------------
// CSR scans.
__global__ void scan_local(const int* __restrict__ deg, int* __restrict__ rowstart,
                           int* __restrict__ psum) {
    __shared__ int s[256];
    const int b = blockIdx.x, t = threadIdx.x, i = b * 256 + t;
    const int v = (i < N_NODES) ? deg[i] : 0;
    s[t] = v;
    __syncthreads();
    for (int off = 1; off < 256; off <<= 1) {
        const int xr = (t >= off) ? s[t - off] : 0;
        __syncthreads();
        s[t] += xr;
        __syncthreads();
    }
    if (i < N_NODES) rowstart[i] = s[t] - v;  // exclusive within block
    if (t == 255) psum[b] = s[255];
}

__global__ void scan_add(int* __restrict__ rowstart, const int* __restrict__ psum) {
    __shared__ int s[256];
    __shared__ int ex[256];
    const int b = blockIdx.x, t = threadIdx.x;
    const int v = (t < NB_SCAN) ? psum[t] : 0;
    s[t] = v;
    __syncthreads();
    for (int off = 1; off < 256; off <<= 1) {
        const int xr = (t >= off) ? s[t - off] : 0;
        __syncthreads();
        s[t] += xr;
        __syncthreads();
    }
    ex[t] = s[t] - v;   // exclusive
    __syncthreads();
    const int i = b * 256 + t;
    if (i < N_NODES) rowstart[i] += ex[b];
}

// ---------------------------------------------------------------------------
// scatter_proj: FUSED edge scatter (blocks < SCAT_BLKS) + MFMA node
// projection PB = bf16([x@G | x@M2pad]) (remaining blocks, 4 wave-tiles).
__global__ void __launch_bounds__(256) scatter_proj(
        const int* __restrict__ src, const int* __restrict__ dst,
        const float* __restrict__ ea,
        const int* __restrict__ rowstart, int* __restrict__ cursor,
        uint* __restrict__ EREC,
        const float* __restrict__ x,
        const ushort_t* __restrict__ NPB,
        ushort_t* __restrict__ PB,
        ushort_t* __restrict__ xb) {
    const int bid = blockIdx.x;
    const int t = threadIdx.x;
    if (bid < SCAT_BLKS) {
        // ---- scatter: 32B records [bf16 ea[11], pad0, int src, pad0] ----
        const int e = bid * 256 + t;
        const int d = dst[e];
        const int pos = atomicAdd(&cursor[d], 1);
        const size_t idx = (size_t)rowstart[d] + pos;
        const float* in = ea + (size_t)e * ED;
        uint w[8];
        #pragma unroll
        for (int jj = 0; jj < 5; ++jj)
            w[jj] = (uint)f2bf(in[2 * jj]) | ((uint)f2bf(in[2 * jj + 1]) << 16);
        w[5] = (uint)f2bf(in[10]);
        w[6] = (uint)src[e];
        w[7] = 0u;
        uint4* o = (uint4*)(EREC + idx * 8);
        o[0] = make_uint4(w[0], w[1], w[2], w[3]);
        o[1] = make_uint4(w[4], w[5], w[6], w[7]);
        return;
    }
    // ---- node projection: PB[n][320] = bf16(x@[G|M2]), xb = bf16(x) ----
    const int lane = t & 63;
    const int tile = (bid - SCAT_BLKS) * 4 + (t >> 6);
    if (tile >= NTILE) return;
    const int n0 = tile * 16;
    const int m = lane & 15, kb = (lane >> 4) * 8;

    short8 a[2];
    #pragma unroll
    for (int ks = 0; ks < 2; ++ks) {
        const float* px = x + (size_t)(n0 + m) * DIN + ks * 32 + kb;
        const float4 u = *(const float4*)px;
        const float4 w4 = *(const float4*)(px + 4);
        short8 av;
        av[0] = (short)f2bf(u.x); av[1] = (short)f2bf(u.y);
        av[2] = (short)f2bf(u.z); av[3] = (short)f2bf(u.w);
        av[4] = (short)f2bf(w4.x); av[5] = (short)f2bf(w4.y);
        av[6] = (short)f2bf(w4.z); av[7] = (short)f2bf(w4.w);
        a[ks] = av;
        *(short8*)(xb + (size_t)(n0 + m) * DIN + ks * 32 + kb) = av;
    }

    const short8* NB = (const short8*)NPB;
    const int rw = (lane >> 4) * 4, cc = lane & 15;

    #pragma unroll
    for (int ct = 0; ct < 20; ++ct) {
        f32x4 c = {0.f, 0.f, 0.f, 0.f};
        c = __builtin_amdgcn_mfma_f32_16x16x32_bf16(a[0], NB[(ct * 2 + 0) * 64 + lane], c, 0, 0, 0);
        c = __builtin_amdgcn_mfma_f32_16x16x32_bf16(a[1], NB[(ct * 2 + 1) * 64 + lane], c, 0, 0, 0);
        #pragma unroll
        for (int r = 0; r < 4; ++r)
            PB[(size_t)(n0 + rw + r) * 320 + ct * 16 + cc] = f2bf(c[r]);
    }
}

// ---------------------------------------------------------------------------
// K2 (MFMA attention): per dst node, chunks of 16 edges. 3 MFMAs compute
// alpha[16e][4h] = [x_src|ea|0] @ [P_h|QWE_h|0] (K=96); masked exp on D
// lanes; x/ea tiles staged in per-wave LDS (padded rows, <=2-way banks);
// PV accumulate on VALU from LDS. No shuffles, no cross-wave barrier.
// NaN-hazard fix: every A element is a FINITE bf16 (a2 built with explicit
// zeros; raw record bits like the src int may form Inf/NaN patterns and
// 0*NaN = NaN in MFMA).
__global__ void __launch_bounds__(256) attnM(const uint* __restrict__ EREC,
                      const ushort_t* __restrict__ PB,
                      const ushort_t* __restrict__ xb,
                      const int* __restrict__ rowstart,
                      const int* __restrict__ deg,
                      ushort_t* __restrict__ AROW) {
    __shared__ ushort_t XT[4][16][72];    // x tile, pad 64->72 (9216 B)
    __shared__ ushort_t EAT[4][16][24];   // ea tile, pad 16->24 (3072 B)
    __shared__ float    EXS[4][4][16];    // ex[h][e] (1024 B)
    const int t = threadIdx.x;
    const int lane = t & 63;
    const int wid = t >> 6;
    const int n = blockIdx.x * 4 + wid;   // N_NODES % 4 == 0
    const int q = lane >> 4;              // k-octet (MFMA) / head (PV)
    const int e = lane & 15;              // A-row,B-col (MFMA) / slot j (PV)
    const int h = q, j = e;

    const int beg = __builtin_amdgcn_readfirstlane(rowstart[n]);
    const int dc  = __builtin_amdgcn_readfirstlane(deg[n]);

    // B fragments (per node): cols 0..3 = heads, rest zero.
    const ushort_t* pb = PB + (size_t)n * 320;
    short8 b0 = {0,0,0,0,0,0,0,0}, b1 = b0, b2 = b0;
    if (e < 4) {
        b0 = *(const short8*)(pb + e * 64 + q * 8);
        b1 = *(const short8*)(pb + e * 64 + 32 + q * 8);
        if (q < 2) b2 = *(const short8*)(pb + 256 + e * 16 + q * 8);
    }

    float4 acc = {0.f, 0.f, 0.f, 0.f};
    float den = 0.f, Tacc = 0.f;

    for (int cbase = 0; cbase < dc; cbase += 16) {
        const int g = cbase + e;
        const int idx = beg + ((g < dc) ? g : 0);       // clamp: masked later
        const uint* rec = EREC + (size_t)idx * 8;
        const int s = (int)rec[6];
        const ushort_t* xr = xb + (size_t)s * DIN;
        const short8 a0 = *(const short8*)(xr + q * 8);          // k 0..31
        const short8 a1 = *(const short8*)(xr + 32 + q * 8);     // k 32..63

        // k 64..95: [ea0..ea10 | 0...]; build with explicit zeros (finite bf16)
        short8 a2 = {0, 0, 0, 0, 0, 0, 0, 0};
        if (q == 0) {
            a2 = *(const short8*)((const ushort_t*)rec);         // ea0..ea7
        } else if (q == 1) {
            const ushort4 t4 = *(const ushort4*)((const ushort_t*)rec + 8);  // ea8,ea9,ea10,0
            a2[0] = (short)t4.x; a2[1] = (short)t4.y;
            a2[2] = (short)t4.z; a2[3] = (short)t4.w;
        }

        *(short8*)(&XT[wid][e][q * 8]) = a0;
        *(short8*)(&XT[wid][e][32 + q * 8]) = a1;
        if (q < 2) *(short8*)(&EAT[wid][e][q * 8]) = a2;

        f32x4 al = {0.f, 0.f, 0.f, 0.f};
        al = __builtin_amdgcn_mfma_f32_16x16x32_bf16(a0, b0, al, 0, 0, 0);
        al = __builtin_amdgcn_mfma_f32_16x16x32_bf16(a1, b1, al, 0, 0, 0);
        al = __builtin_amdgcn_mfma_f32_16x16x32_bf16(a2, b2, al, 0, 0, 0);

        if (e < 4) {   // D cols 0..3 hold heads; rows = q*4+r
            #pragma unroll
            for (int r = 0; r < 4; ++r) {
                const int er = q * 4 + r;
                EXS[wid][e][er] = (cbase + er < dc) ? __expf(al[r] * 0.125f) : 0.f;
            }
        }
        asm volatile("s_waitcnt lgkmcnt(0)" ::: "memory");  // same-wave LDS fence

        const f32x4 x0 = *(const f32x4*)(&EXS[wid][h][0]);
        const f32x4 x1 = *(const f32x4*)(&EXS[wid][h][4]);
        const f32x4 x2 = *(const f32x4*)(&EXS[wid][h][8]);
        const f32x4 x3 = *(const f32x4*)(&EXS[wid][h][12]);
        const float exs[16] = {x0[0],x0[1],x0[2],x0[3], x1[0],x1[1],x1[2],x1[3],
                               x2[0],x2[1],x2[2],x2[3], x3[0],x3[1],x3[2],x3[3]};
        #pragma unroll
        for (int ee = 0; ee < 16; ++ee) {
            const float ex = exs[ee];
            const ushort4 xv = *(const ushort4*)(&XT[wid][ee][j * 4]);
            acc.x = fmaf(ex, bf2f(xv.x), acc.x);
            acc.y = fmaf(ex, bf2f(xv.y), acc.y);
            acc.z = fmaf(ex, bf2f(xv.z), acc.z);
            acc.w = fmaf(ex, bf2f(xv.w), acc.w);
            den += ex;
            const float eaj = (j < ED) ? bf2f(EAT[wid][ee][j]) : 0.f;
            Tacc = fmaf(ex, eaj, Tacc);
        }
    }

    const float inv = (den > 0.f) ? 1.f / den : 0.f;
    ushort_t* arow = AROW + (size_t)n * 384;
    ushort4 ob;
    ob.x = f2bf(acc.x * inv); ob.y = f2bf(acc.y * inv);
    ob.z = f2bf(acc.z * inv); ob.w = f2bf(acc.w * inv);
    *(ushort4*)(arow + lane * 4) = ob;                    // xagg segment
    if (lane < 8) {                                       // x segment (bf16 x copy)
        const uint4 v = *(const uint4*)(xb + (size_t)n * DIN + lane * 8);
        *(uint4*)(arow + 256 + lane * 8) = v;
    }
    if (j < ED) arow[320 + h * 11 + j] = f2bf(Tacc * inv);  // TO segment
    if (lane >= 44) arow[320 + lane] = 0;                   // pad 364..383
}

// ---------------------------------------------------------------------------
// K3 (MFMA): y = AROW @ WFT (K=384, N=64). 1 wave = 16 nodes.
__global__ void __launch_bounds__(64) finalizeM(const ushort_t* __restrict__ AROW,
                                                const ushort_t* __restrict__ WFB,
                                                float* __restrict__ y) {
    const int lane = threadIdx.x;
    const int n0 = blockIdx.x * 16;
    const int m = lane & 15, kb = (lane >> 4) * 8;
    const short8* WB = (const short8*)WFB;

    f32x4 a0 = {0.f, 0.f, 0.f, 0.f}, a1 = a0, a2 = a0, a3 = a0;
    #pragma unroll
    for (int ks = 0; ks < 12; ++ks) {
        const short8 av = *(const short8*)(AROW + (size_t)(n0 + m) * 384 + ks * 32 + kb);
        a0 = __builtin_amdgcn_mfma_f32_16x16x32_bf16(av, WB[(ks * 4 + 0) * 64 + lane], a0, 0, 0, 0);
        a1 = __builtin_amdgcn_mfma_f32_16x16x32_bf16(av, WB[(ks * 4 + 1) * 64 + lane], a1, 0, 0, 0);
        a2 = __builtin_amdgcn_mfma_f32_16x16x32_bf16(av, WB[(ks * 4 + 2) * 64 + lane], a2, 0, 0, 0);
        a3 = __builtin_amdgcn_mfma_f32_16x16x32_bf16(av, WB[(ks * 4 + 3) * 64 + lane], a3, 0, 0, 0);
    }
    const int rw = (lane >> 4) * 4, cc = lane & 15;
    #pragma unroll
    for (int r = 0; r < 4; ++r) {
        float* yr = y + (size_t)(n0 + rw + r) * CPH + cc;
        yr[0]  = a0[r];
        yr[16] = a1[r];
        yr[32] = a2[r];
        yr[48] = a3[r];
    }
}

// ---------------------------------------------------------------------------
extern "C" void kernel_launch(void* const* d_in, const int* in_sizes, int n_in,
                              void* d_out, int out_size, void* d_ws, size_t ws_size,
                              hipStream_t stream) {
    const float* x     = (const float*)d_in[0];
    const float* ea    = (const float*)d_in[1];
    const int*   eidx  = (const int*)  d_in[2];
    const float* Wq    = (const float*)d_in[3];
    const float* Wk    = (const float*)d_in[4];
    const float* Wv    = (const float*)d_in[5];
    const float* We    = (const float*)d_in[6];
    const float* Wskip = (const float*)d_in[7];
    const float* Wlin  = (const float*)d_in[8];
    float* out = (float*)d_out;

    ushort_t* NPB  = (ushort_t*)d_ws;               // 20480 sh
    ushort_t* WFB  = NPB + 20480;                   // 24576 sh
    ushort_t* PB   = WFB + 24576;                   // N*320 sh
    ushort_t* AROW = PB + (size_t)N_NODES * 320;    // N*384 sh
    ushort_t* xb   = AROW + (size_t)N_NODES * 384;  // N*64 sh
    int* deg     = (int*)(xb + (size_t)N_NODES * DIN);  // NPAD
    int* cursor  = deg + NPAD;                      // NPAD (zeroed with deg)
    int* rowstart= cursor + NPAD;                   // NPAD
    int* psum    = rowstart + NPAD;                 // 256
    uint* EREC   = (uint*)(psum + 256);             // E*32B

    const int* src = eidx;
    const int* dst = eidx + N_EDGES;

    hipMemsetAsync(deg, 0, (size_t)2 * NPAD * sizeof(int), stream);
    prep_hist<<<(FOLD_THREADS + N_EDGES + 255) / 256, 256, 0, stream>>>(
        Wq, Wk, Wv, We, Wskip, Wlin, NPB, WFB, dst, deg);
    scan_local<<<NB_SCAN, 256, 0, stream>>>(deg, rowstart, psum);
    scan_add<<<NB_SCAN, 256, 0, stream>>>(rowstart, psum);
    scatter_proj<<<SCAT_BLKS + PROJ_BLKS, 256, 0, stream>>>(
        src, dst, ea, rowstart, cursor, EREC, x, NPB, PB, xb);
    attnM<<<N_NODES / 4, 256, 0, stream>>>(EREC, PB, xb, rowstart, deg, AROW);
    finalizeM<<<N_NODES / 16, 64, 0, stream>>>(AROW, PB /*unused*/ == PB ? WFB : WFB, out);
}

// Round 18
// 163.589 us; speedup vs baseline: 1.3838x; 1.1273x over previous
//
#include <hip/hip_runtime.h>
#include <math.h>

#define N_NODES 50000
#define N_EDGES 800000
#define DIN 64
#define HC 256      // H*C
#define NH 4        // heads
#define CPH 64      // channels per head
#define ED 11
#define NPAD 50176  // 196*256
#define NB_SCAN 196
#define NTILE 3125       // N_NODES/16
#define SCAT_BLKS 3125   // N_EDGES/256
#define PROJ_BLKS 782    // ceil(NTILE/4)
#define FOLD_THREADS 45056

typedef unsigned int uint;
typedef unsigned short ushort_t;
using short8 = __attribute__((ext_vector_type(8))) short;
using f32x4  = __attribute__((ext_vector_type(4))) float;

__device__ __forceinline__ ushort_t f2bf(float f) {
    uint u = __float_as_uint(f);
    u = (u + 0x7FFFu + ((u >> 16) & 1u)) >> 16;   // RTNE
    return (ushort_t)u;
}
__device__ __forceinline__ float bf2f(ushort_t h) {
    return __uint_as_float(((uint)h) << 16);
}

// ---------------------------------------------------------------------------
// prep_hist: weight folds into bf16 MFMA B-fragments + dst-degree histogram
// that ALSO records each edge's slot (epos[e]) so the scatter pass needs no
// atomic. Frag layout (16x16x32): element (k,n) -> lane =
// (n&15)|(((k>>3)&3)<<4), j=k&7, kstep=k>>5; arrays base[f*512+lane*8+j].
__global__ void prep_hist(const float* __restrict__ Wq, const float* __restrict__ Wk,
                          const float* __restrict__ Wv, const float* __restrict__ We,
                          const float* __restrict__ Wskip, const float* __restrict__ Wlin,
                          ushort_t* __restrict__ NPB, ushort_t* __restrict__ WFB,
                          const int* __restrict__ dst, int* __restrict__ deg,
                          int* __restrict__ epos) {
    const int g = blockIdx.x * 256 + threadIdx.x;
    if (g < 16384) {                       // NPB cols 0..255 (G)
        const int d = g >> 8, hc = g & 255;
        const int hb = hc & 192, dp = hc & 63;
        const float* bq = Wq + d * HC + hb;
        const float* bk = Wk + dp * HC + hb;
        float v = 0.f;
        #pragma unroll 8
        for (int c = 0; c < 64; ++c) v = fmaf(bq[c], bk[c], v);
        const int l = (hc & 15) | (((d >> 3) & 3) << 4);
        NPB[(((hc >> 4) * 2 + (d >> 5)) * 64 + l) * 8 + (d & 7)] = f2bf(v);
    } else if (g < 20480) {                // NPB cols 256..319 (QWE fold, padded)
        const int gm = g - 16384;
        const int d = gm >> 6, cm = gm & 63;
        const int h = cm >> 4, jj = cm & 15;
        float v = 0.f;
        if (jj < ED) {
            const float* wq = Wq + d * HC + h * 64;
            const float* we = We + jj * HC + h * 64;
            #pragma unroll 8
            for (int c = 0; c < 64; ++c) v = fmaf(wq[c], we[c], v);
        }
        const int col = 256 + cm;
        const int l = (cm & 15) | (((d >> 3) & 3) << 4);
        NPB[(((col >> 4) * 2 + (d >> 5)) * 64 + l) * 8 + (d & 7)] = f2bf(v);
    } else if (g < 20480 + 24576) {        // WFB: (k<384, o<64)
        const int gm = g - 20480;
        const int k = gm >> 6, o = gm & 63;
        float v = 0.f;
        if (k < 256) {
            const int h = k >> 6, d = k & 63;
            const float* wv = Wv + d * HC + h * 64;
            const float* wl = Wlin + (h * 64) * CPH + o;
            #pragma unroll 8
            for (int c = 0; c < 64; ++c) v = fmaf(wv[c], wl[(size_t)c * CPH], v);
        } else if (k < 320) {
            const int d = k - 256;
            const float* wsk = Wskip + d * HC;
            const float* wl = Wlin + o;
            #pragma unroll 8
            for (int k2 = 0; k2 < 256; ++k2) v = fmaf(wsk[k2], wl[(size_t)k2 * CPH], v);
        } else if (k < 364) {
            const int r = k - 320;
            const int h = r / 11, j = r - h * 11;
            const float* we = We + j * HC + h * 64;
            const float* wl = Wlin + (h * 64) * CPH + o;
            #pragma unroll 8
            for (int c = 0; c < 64; ++c) v = fmaf(we[c], wl[(size_t)c * CPH], v);
        }
        const int l = (o & 15) | (((k >> 3) & 3) << 4);
        WFB[(((k >> 5) * 4 + (o >> 4)) * 64 + l) * 8 + (k & 7)] = f2bf(v);
    } else {                               // histogram + slot assignment
        const int e = g - FOLD_THREADS;
        if (e < N_EDGES) epos[e] = atomicAdd(&deg[dst[e]], 1);
    }
}

// ---------------------------------------------------------------------------
// CSR scans.
__global__ void scan_local(const int* __restrict__ deg, int* __restrict__ rowstart,
                           int* __restrict__ psum) {
    __shared__ int s[256];
    const int b = blockIdx.x, t = threadIdx.x, i = b * 256 + t;
    const int v = (i < N_NODES) ? deg[i] : 0;
    s[t] = v;
    __syncthreads();
    for (int off = 1; off < 256; off <<= 1) {
        const int xr = (t >= off) ? s[t - off] : 0;
        __syncthreads();
        s[t] += xr;
        __syncthreads();
    }
    if (i < N_NODES) rowstart[i] = s[t] - v;  // exclusive within block
    if (t == 255) psum[b] = s[255];
}

__global__ void scan_add(int* __restrict__ rowstart, const int* __restrict__ psum) {
    __shared__ int s[256];
    __shared__ int ex[256];
    const int b = blockIdx.x, t = threadIdx.x;
    const int v = (t < NB_SCAN) ? psum[t] : 0;
    s[t] = v;
    __syncthreads();
    for (int off = 1; off < 256; off <<= 1) {
        const int xr = (t >= off) ? s[t - off] : 0;
        __syncthreads();
        s[t] += xr;
        __syncthreads();
    }
    ex[t] = s[t] - v;   // exclusive
    __syncthreads();
    const int i = b * 256 + t;
    if (i < N_NODES) rowstart[i] += ex[b];
}

// ---------------------------------------------------------------------------
// scatter_proj: FUSED edge scatter (blocks < SCAT_BLKS; NO atomics — slot is
// rowstart[dst] + epos) + MFMA node projection (remaining blocks).
__global__ void __launch_bounds__(256) scatter_proj(
        const int* __restrict__ src, const int* __restrict__ dst,
        const float* __restrict__ ea,
        const int* __restrict__ rowstart, const int* __restrict__ epos,
        uint* __restrict__ EREC,
        const float* __restrict__ x,
        const ushort_t* __restrict__ NPB,
        ushort_t* __restrict__ PB,
        ushort_t* __restrict__ xb) {
    const int bid = blockIdx.x;
    const int t = threadIdx.x;
    if (bid < SCAT_BLKS) {
        // ---- scatter: 32B records [bf16 ea[11], pad0, int src, pad0] ----
        const int e = bid * 256 + t;
        const size_t idx = (size_t)rowstart[dst[e]] + epos[e];
        const float* in = ea + (size_t)e * ED;
        uint w[8];
        #pragma unroll
        for (int jj = 0; jj < 5; ++jj)
            w[jj] = (uint)f2bf(in[2 * jj]) | ((uint)f2bf(in[2 * jj + 1]) << 16);
        w[5] = (uint)f2bf(in[10]);
        w[6] = (uint)src[e];
        w[7] = 0u;
        uint4* o = (uint4*)(EREC + idx * 8);
        o[0] = make_uint4(w[0], w[1], w[2], w[3]);
        o[1] = make_uint4(w[4], w[5], w[6], w[7]);
        return;
    }
    // ---- node projection: PB[n][320] = bf16(x@[G|M2]), xb = bf16(x) ----
    const int lane = t & 63;
    const int tile = (bid - SCAT_BLKS) * 4 + (t >> 6);
    if (tile >= NTILE) return;
    const int n0 = tile * 16;
    const int m = lane & 15, kb = (lane >> 4) * 8;

    short8 a[2];
    #pragma unroll
    for (int ks = 0; ks < 2; ++ks) {
        const float* px = x + (size_t)(n0 + m) * DIN + ks * 32 + kb;
        const float4 u = *(const float4*)px;
        const float4 w4 = *(const float4*)(px + 4);
        short8 av;
        av[0] = (short)f2bf(u.x); av[1] = (short)f2bf(u.y);
        av[2] = (short)f2bf(u.z); av[3] = (short)f2bf(u.w);
        av[4] = (short)f2bf(w4.x); av[5] = (short)f2bf(w4.y);
        av[6] = (short)f2bf(w4.z); av[7] = (short)f2bf(w4.w);
        a[ks] = av;
        *(short8*)(xb + (size_t)(n0 + m) * DIN + ks * 32 + kb) = av;
    }

    const short8* NB = (const short8*)NPB;
    const int rw = (lane >> 4) * 4, cc = lane & 15;

    #pragma unroll
    for (int ct = 0; ct < 20; ++ct) {
        f32x4 c = {0.f, 0.f, 0.f, 0.f};
        c = __builtin_amdgcn_mfma_f32_16x16x32_bf16(a[0], NB[(ct * 2 + 0) * 64 + lane], c, 0, 0, 0);
        c = __builtin_amdgcn_mfma_f32_16x16x32_bf16(a[1], NB[(ct * 2 + 1) * 64 + lane], c, 0, 0, 0);
        #pragma unroll
        for (int r = 0; r < 4; ++r)
            PB[(size_t)(n0 + rw + r) * 320 + ct * 16 + cc] = f2bf(c[r]);
    }
}

// ---------------------------------------------------------------------------
// K2 (MFMA attention): per dst node, chunks of 16 edges. 3 MFMAs compute
// alpha[16e][4h] = [x_src|ea|0] @ [P_h|QWE_h|0] (K=96); masked exp on D
// lanes; x/ea tiles staged in per-wave LDS (padded rows, <=2-way banks);
// PV accumulate on VALU from LDS. No shuffles, no cross-wave barrier.
// All A elements are FINITE bf16 (0*NaN=NaN hazard avoided).
__global__ void __launch_bounds__(256) attnM(const uint* __restrict__ EREC,
                      const ushort_t* __restrict__ PB,
                      const ushort_t* __restrict__ xb,
                      const int* __restrict__ rowstart,
                      const int* __restrict__ deg,
                      ushort_t* __restrict__ AROW) {
    __shared__ ushort_t XT[4][16][72];    // x tile, pad 64->72 (9216 B)
    __shared__ ushort_t EAT[4][16][24];   // ea tile, pad 16->24 (3072 B)
    __shared__ float    EXS[4][4][16];    // ex[h][e] (1024 B)
    const int t = threadIdx.x;
    const int lane = t & 63;
    const int wid = t >> 6;
    const int n = blockIdx.x * 4 + wid;   // N_NODES % 4 == 0
    const int q = lane >> 4;              // k-octet (MFMA) / head (PV)
    const int e = lane & 15;              // A-row,B-col (MFMA) / slot j (PV)
    const int h = q, j = e;

    const int beg = __builtin_amdgcn_readfirstlane(rowstart[n]);
    const int dc  = __builtin_amdgcn_readfirstlane(deg[n]);

    // B fragments (per node): cols 0..3 = heads, rest zero.
    const ushort_t* pb = PB + (size_t)n * 320;
    short8 b0 = {0,0,0,0,0,0,0,0}, b1 = b0, b2 = b0;
    if (e < 4) {
        b0 = *(const short8*)(pb + e * 64 + q * 8);
        b1 = *(const short8*)(pb + e * 64 + 32 + q * 8);
        if (q < 2) b2 = *(const short8*)(pb + 256 + e * 16 + q * 8);
    }

    float4 acc = {0.f, 0.f, 0.f, 0.f};
    float den = 0.f, Tacc = 0.f;

    for (int cbase = 0; cbase < dc; cbase += 16) {
        const int g = cbase + e;
        const int idx = beg + ((g < dc) ? g : 0);       // clamp: masked later
        const uint* rec = EREC + (size_t)idx * 8;
        const int s = (int)rec[6];
        const ushort_t* xr = xb + (size_t)s * DIN;
        const short8 a0 = *(const short8*)(xr + q * 8);          // k 0..31
        const short8 a1 = *(const short8*)(xr + 32 + q * 8);     // k 32..63

        // k 64..95: [ea0..ea10 | 0...]; build with explicit zeros (finite bf16)
        short8 a2 = {0, 0, 0, 0, 0, 0, 0, 0};
        if (q == 0) {
            a2 = *(const short8*)((const ushort_t*)rec);         // ea0..ea7
        } else if (q == 1) {
            const ushort4 t4 = *(const ushort4*)((const ushort_t*)rec + 8);  // ea8,ea9,ea10,0
            a2[0] = (short)t4.x; a2[1] = (short)t4.y;
            a2[2] = (short)t4.z; a2[3] = (short)t4.w;
        }

        *(short8*)(&XT[wid][e][q * 8]) = a0;
        *(short8*)(&XT[wid][e][32 + q * 8]) = a1;
        if (q < 2) *(short8*)(&EAT[wid][e][q * 8]) = a2;

        f32x4 al = {0.f, 0.f, 0.f, 0.f};
        al = __builtin_amdgcn_mfma_f32_16x16x32_bf16(a0, b0, al, 0, 0, 0);
        al = __builtin_amdgcn_mfma_f32_16x16x32_bf16(a1, b1, al, 0, 0, 0);
        al = __builtin_amdgcn_mfma_f32_16x16x32_bf16(a2, b2, al, 0, 0, 0);

        if (e < 4) {   // D cols 0..3 hold heads; rows = q*4+r
            #pragma unroll
            for (int r = 0; r < 4; ++r) {
                const int er = q * 4 + r;
                EXS[wid][e][er] = (cbase + er < dc) ? __expf(al[r] * 0.125f) : 0.f;
            }
        }
        asm volatile("s_waitcnt lgkmcnt(0)" ::: "memory");  // same-wave LDS fence

        const f32x4 x0 = *(const f32x4*)(&EXS[wid][h][0]);
        const f32x4 x1 = *(const f32x4*)(&EXS[wid][h][4]);
        const f32x4 x2 = *(const f32x4*)(&EXS[wid][h][8]);
        const f32x4 x3 = *(const f32x4*)(&EXS[wid][h][12]);
        const float exs[16] = {x0[0],x0[1],x0[2],x0[3], x1[0],x1[1],x1[2],x1[3],
                               x2[0],x2[1],x2[2],x2[3], x3[0],x3[1],x3[2],x3[3]};
        #pragma unroll
        for (int ee = 0; ee < 16; ++ee) {
            const float ex = exs[ee];
            const ushort4 xv = *(const ushort4*)(&XT[wid][ee][j * 4]);
            acc.x = fmaf(ex, bf2f(xv.x), acc.x);
            acc.y = fmaf(ex, bf2f(xv.y), acc.y);
            acc.z = fmaf(ex, bf2f(xv.z), acc.z);
            acc.w = fmaf(ex, bf2f(xv.w), acc.w);
            den += ex;
            const float eaj = (j < ED) ? bf2f(EAT[wid][ee][j]) : 0.f;
            Tacc = fmaf(ex, eaj, Tacc);
        }
    }

    const float inv = (den > 0.f) ? 1.f / den : 0.f;
    ushort_t* arow = AROW + (size_t)n * 384;
    ushort4 ob;
    ob.x = f2bf(acc.x * inv); ob.y = f2bf(acc.y * inv);
    ob.z = f2bf(acc.z * inv); ob.w = f2bf(acc.w * inv);
    *(ushort4*)(arow + lane * 4) = ob;                    // xagg segment
    if (lane < 8) {                                       // x segment (bf16 x copy)
        const uint4 v = *(const uint4*)(xb + (size_t)n * DIN + lane * 8);
        *(uint4*)(arow + 256 + lane * 8) = v;
    }
    if (j < ED) arow[320 + h * 11 + j] = f2bf(Tacc * inv);  // TO segment
    if (lane >= 44) arow[320 + lane] = 0;                   // pad 364..383
}

// ---------------------------------------------------------------------------
// K3 (MFMA): y = AROW @ WFT (K=384, N=64). 1 wave = 16 nodes.
__global__ void __launch_bounds__(64) finalizeM(const ushort_t* __restrict__ AROW,
                                                const ushort_t* __restrict__ WFB,
                                                float* __restrict__ y) {
    const int lane = threadIdx.x;
    const int n0 = blockIdx.x * 16;
    const int m = lane & 15, kb = (lane >> 4) * 8;
    const short8* WB = (const short8*)WFB;

    f32x4 a0 = {0.f, 0.f, 0.f, 0.f}, a1 = a0, a2 = a0, a3 = a0;
    #pragma unroll
    for (int ks = 0; ks < 12; ++ks) {
        const short8 av = *(const short8*)(AROW + (size_t)(n0 + m) * 384 + ks * 32 + kb);
        a0 = __builtin_amdgcn_mfma_f32_16x16x32_bf16(av, WB[(ks * 4 + 0) * 64 + lane], a0, 0, 0, 0);
        a1 = __builtin_amdgcn_mfma_f32_16x16x32_bf16(av, WB[(ks * 4 + 1) * 64 + lane], a1, 0, 0, 0);
        a2 = __builtin_amdgcn_mfma_f32_16x16x32_bf16(av, WB[(ks * 4 + 2) * 64 + lane], a2, 0, 0, 0);
        a3 = __builtin_amdgcn_mfma_f32_16x16x32_bf16(av, WB[(ks * 4 + 3) * 64 + lane], a3, 0, 0, 0);
    }
    const int rw = (lane >> 4) * 4, cc = lane & 15;
    #pragma unroll
    for (int r = 0; r < 4; ++r) {
        float* yr = y + (size_t)(n0 + rw + r) * CPH + cc;
        yr[0]  = a0[r];
        yr[16] = a1[r];
        yr[32] = a2[r];
        yr[48] = a3[r];
    }
}

// ---------------------------------------------------------------------------
extern "C" void kernel_launch(void* const* d_in, const int* in_sizes, int n_in,
                              void* d_out, int out_size, void* d_ws, size_t ws_size,
                              hipStream_t stream) {
    const float* x     = (const float*)d_in[0];
    const float* ea    = (const float*)d_in[1];
    const int*   eidx  = (const int*)  d_in[2];
    const float* Wq    = (const float*)d_in[3];
    const float* Wk    = (const float*)d_in[4];
    const float* Wv    = (const float*)d_in[5];
    const float* We    = (const float*)d_in[6];
    const float* Wskip = (const float*)d_in[7];
    const float* Wlin  = (const float*)d_in[8];
    float* out = (float*)d_out;

    ushort_t* NPB  = (ushort_t*)d_ws;               // 20480 sh
    ushort_t* WFB  = NPB + 20480;                   // 24576 sh
    ushort_t* PB   = WFB + 24576;                   // N*320 sh
    ushort_t* AROW = PB + (size_t)N_NODES * 320;    // N*384 sh
    ushort_t* xb   = AROW + (size_t)N_NODES * 384;  // N*64 sh
    int* deg     = (int*)(xb + (size_t)N_NODES * DIN);  // NPAD (memset to 0)
    int* rowstart= deg + NPAD;                      // NPAD
    int* psum    = rowstart + NPAD;                 // 256
    int* epos    = psum + 256;                      // E
    uint* EREC   = (uint*)(epos + N_EDGES);         // E*32B

    const int* src = eidx;
    const int* dst = eidx + N_EDGES;

    hipMemsetAsync(deg, 0, (size_t)NPAD * sizeof(int), stream);
    prep_hist<<<(FOLD_THREADS + N_EDGES + 255) / 256, 256, 0, stream>>>(
        Wq, Wk, Wv, We, Wskip, Wlin, NPB, WFB, dst, deg, epos);
    scan_local<<<NB_SCAN, 256, 0, stream>>>(deg, rowstart, psum);
    scan_add<<<NB_SCAN, 256, 0, stream>>>(rowstart, psum);
    scatter_proj<<<SCAT_BLKS + PROJ_BLKS, 256, 0, stream>>>(
        src, dst, ea, rowstart, epos, EREC, x, NPB, PB, xb);
    attnM<<<N_NODES / 4, 256, 0, stream>>>(EREC, PB, xb, rowstart, deg, AROW);
    finalizeM<<<N_NODES / 16, 64, 0, stream>>>(AROW, WFB, out);
}